// Round 5
// baseline (426.406 us; speedup 1.0000x reference)
//
#include <hip/hip_runtime.h>

#define HIDDEN 128
#define LN_EPS 1e-5f
#define PAD_K 136   // 128 + 8 shorts pad: row stride 272 B (16B-aligned rows)
#define SLOT 64     // padded adjacency slots/parent; P(Poisson(6) > 64) ~ 1e-40

typedef __attribute__((ext_vector_type(8))) short short8;
typedef __attribute__((ext_vector_type(4))) float floatx4;
typedef __attribute__((ext_vector_type(4))) unsigned short ushortx4;

__device__ __forceinline__ unsigned short f2bf(float f) {
    unsigned u = __builtin_bit_cast(unsigned, f);
    u += 0x7fff + ((u >> 16) & 1);          // round-to-nearest-even
    return (unsigned short)(u >> 16);
}
__device__ __forceinline__ float bf2f(unsigned short h) {
    unsigned u = ((unsigned)h) << 16;
    return __builtin_bit_cast(float, u);
}

// ============================================================================
// Edge scatter: padded-slot adjacency build (one kernel, int atomics only).
// ============================================================================
__global__ __launch_bounds__(256) void edge_scatter_pad(
    const int* __restrict__ src, const int* __restrict__ dst,
    int* __restrict__ cnt_i, int* __restrict__ slots, int E)
{
    int e = blockIdx.x * 256 + threadIdx.x;
    if (e < E) {
        int s = src[e];
        int pos = atomicAdd(&cnt_i[s], 1);
        if (pos < SLOT) slots[s * SLOT + pos] = dst[e];
    }
}

// ============================================================================
// Pack x_child -> bf16 pairs in the gather/epilogue lane layout:
// lane l covers cols c0 = (l/16)*32 + l%16 and c1 = c0 + 16.
// xcp[d][l] = (bf16(row[c1]) << 16) | bf16(row[c0]).
// 51.2 MB result is L3-resident; gather then needs ONE dword per lane/edge.
// ============================================================================
__global__ __launch_bounds__(256) void pack_xc(
    const float* __restrict__ xc, unsigned* __restrict__ xcp, int Nc)
{
    int r = blockIdx.x * 4 + (threadIdx.x >> 6);
    int lane = threadIdx.x & 63;
    if (r >= Nc) return;
    int c0 = ((lane >> 4) << 5) + (lane & 15);
    const float* row = xc + (size_t)r * HIDDEN;
    float a = row[c0], b = row[c0 + 16];
    xcp[(size_t)r * 64 + lane] = ((unsigned)f2bf(b) << 16) | (unsigned)f2bf(a);
}

// ============================================================================
// Weight prep: fp32 [k][n] -> bf16 transposed [n][k] (K-contiguous B-frags)
// ============================================================================
__global__ __launch_bounds__(256) void prep_weights(
    const float* __restrict__ W1, const float* __restrict__ W2,
    const float* __restrict__ Wu,
    unsigned short* __restrict__ W1t, unsigned short* __restrict__ W2t,
    unsigned short* __restrict__ Wut)
{
    int e = blockIdx.x * 256 + threadIdx.x;
    if (e >= HIDDEN * HIDDEN) return;
    int k = e >> 7, n = e & 127;
    W1t[n * HIDDEN + k] = f2bf(W1[e]);
    W2t[n * HIDDEN + k] = f2bf(W2[e]);
    Wut[n * HIDDEN + k] = f2bf(Wu[e]);
}

// ============================================================================
// Fused parent kernel: gather-mean + 3 MFMA GEMMs + LayerNorm.
// 64 rows/block, 4 waves; wave w owns cols [32w, 32w+32) in the GEMMs and
// gathers means for parents [16w, 16w+16). 16x16x32 bf16 MFMA;
// A[m=lane&15][k=quad*8+j], B[k][n=lane&15], D: col=lane&15, row=quad*4+reg.
// ============================================================================
__device__ __forceinline__ void gemm16(
    const unsigned short* __restrict__ Wt,   // [128][128] bf16, n-major
    const unsigned short* actSrc,            // LDS [64][PAD_K] bf16
    int w, int quad, int nl, floatx4 acc[4][2])
{
    short8 b[2][4];
    #pragma unroll
    for (int nt = 0; nt < 2; nt++)
        #pragma unroll
        for (int kc = 0; kc < 4; kc++)
            b[nt][kc] = *(const short8*)(Wt + (w * 32 + nt * 16 + nl) * HIDDEN
                                            + kc * 32 + quad * 8);
    #pragma unroll
    for (int mt = 0; mt < 4; mt++)
        #pragma unroll
        for (int nt = 0; nt < 2; nt++)
            acc[mt][nt] = (floatx4){0.f, 0.f, 0.f, 0.f};

    #pragma unroll
    for (int kc = 0; kc < 4; kc++) {
        short8 a[4];
        #pragma unroll
        for (int mt = 0; mt < 4; mt++)
            a[mt] = *(const short8*)(actSrc + (mt * 16 + nl) * PAD_K
                                            + kc * 32 + quad * 8);
        #pragma unroll
        for (int mt = 0; mt < 4; mt++)
            #pragma unroll
            for (int nt = 0; nt < 2; nt++)
                acc[mt][nt] = __builtin_amdgcn_mfma_f32_16x16x32_bf16(
                    a[mt], b[nt][kc], acc[mt][nt], 0, 0, 0);
    }
}

__global__ __launch_bounds__(256) void parent_fused(
    const float* __restrict__ xp,
    const unsigned short* __restrict__ W1t, const float* __restrict__ b1,
    const unsigned short* __restrict__ W2t, const float* __restrict__ b2,
    const unsigned short* __restrict__ Wut, const float* __restrict__ bu,
    const float* __restrict__ gamma, const float* __restrict__ beta,
    const int* __restrict__ slots, const int* __restrict__ cnt_i,
    const unsigned* __restrict__ xcp, const float* __restrict__ xcf,
    int usePacked, float* __restrict__ out, int Np)
{
    __shared__ __align__(16) unsigned short xbuf[64 * PAD_K];  // bf16 x (kept)
    __shared__ __align__(16) unsigned short act[64 * PAD_K];   // h, then agg
    __shared__ unsigned meanb[64 * 64];   // [m][lane] packed bf16 mean pair
    __shared__ float lnS[64][4];
    __shared__ float lnQ[64][4];
    __shared__ float lnMu[64];
    __shared__ float lnRs[64];
    __shared__ float cnLds[64];

    const int t    = threadIdx.x;
    const int w    = t >> 6;
    const int lane = t & 63;
    const int quad = lane >> 4;
    const int nl   = lane & 15;
    const int row0 = blockIdx.x * 64;
    int nrow = Np - row0; if (nrow > 64) nrow = 64;

    // ---- counts for this block's 64 parents ----
    if (t < 64) cnLds[t] = (row0 + t < Np) ? (float)cnt_i[row0 + t] : 0.f;

    // ---- stage x -> bf16 xbuf (zero-fill padded rows) ----
    {
        const float4* g = (const float4*)(xp + (size_t)row0 * HIDDEN);
        #pragma unroll
        for (int i = 0; i < 8; i++) {
            int v  = t + i * 256;     // float4 index 0..2047
            int r  = v >> 5;          // row (32 float4 per row)
            int c4 = v & 31;
            float4 xv = (r < nrow) ? g[v] : make_float4(0.f, 0.f, 0.f, 0.f);
            ushortx4 pk = { f2bf(xv.x), f2bf(xv.y), f2bf(xv.z), f2bf(xv.w) };
            *(ushortx4*)&xbuf[r * PAD_K + c4 * 4] = pk;
        }
    }
    __syncthreads();

    // ---- gather phase: wave w -> parents [16w, 16w+16). Lane l covers cols
    //      c0=(l/16)*32+l%16, c1=c0+16, matching meanb consumer layout.
    //      2-deep pipelined over edges; source is L3-resident packed bf16. ----
    {
        int c0 = ((lane >> 4) << 5) + (lane & 15);
        for (int j = 0; j < 16; j++) {
            int m = w * 16 + j;
            int p = row0 + m;
            float cn = cnLds[m];
            int c = (int)cn; if (c > SLOT) c = SLOT;
            int idx = (lane < c && p < Np) ? slots[(size_t)p * SLOT + lane] : 0;
            float a = 0.f, b = 0.f;
            if (usePacked) {
                int i = 0;
                for (; i + 2 <= c; i += 2) {
                    int d0 = __shfl(idx, i, 64);
                    int d1 = __shfl(idx, i + 1, 64);
                    unsigned u0 = xcp[(size_t)d0 * 64 + lane];
                    unsigned u1 = xcp[(size_t)d1 * 64 + lane];
                    a += bf2f((unsigned short)(u0 & 0xffff))
                       + bf2f((unsigned short)(u1 & 0xffff));
                    b += bf2f((unsigned short)(u0 >> 16))
                       + bf2f((unsigned short)(u1 >> 16));
                }
                if (i < c) {
                    unsigned u0 = xcp[(size_t)__shfl(idx, i, 64) * 64 + lane];
                    a += bf2f((unsigned short)(u0 & 0xffff));
                    b += bf2f((unsigned short)(u0 >> 16));
                }
            } else {
                for (int i = 0; i < c; i++) {
                    int d = __shfl(idx, i, 64);
                    const float* row = xcf + (size_t)d * HIDDEN;
                    a += row[c0];
                    b += row[c0 + 16];
                }
            }
            float inv = 1.0f / fmaxf(cn, 1.0f);
            meanb[m * 64 + lane] =
                ((unsigned)f2bf(b * inv) << 16) | (unsigned)f2bf(a * inv);
        }
    }
    // (no barrier needed here: the GEMM1-epilogue barrier below orders
    //  meanb writes before any cross-wave read in the GEMM2 epilogue)

    floatx4 acc[4][2];

    // ---- GEMM1: h = relu(x @ W1 + b1) -> act ----
    gemm16(W1t, xbuf, w, quad, nl, acc);
    {
        float bb0 = b1[w * 32 + nl], bb1 = b1[w * 32 + 16 + nl];
        #pragma unroll
        for (int mt = 0; mt < 4; mt++)
            #pragma unroll
            for (int r = 0; r < 4; r++) {
                int m = mt * 16 + quad * 4 + r;
                float h0 = fmaxf(acc[mt][0][r] + bb0, 0.f);
                float h1 = fmaxf(acc[mt][1][r] + bb1, 0.f);
                act[m * PAD_K + w * 32 + nl]      = f2bf(h0);
                act[m * PAD_K + w * 32 + 16 + nl] = f2bf(h1);
            }
    }
    __syncthreads();

    // ---- GEMM2: pred = h @ W2 + b2; agg = mean - pred*[cnt>0] ----
    gemm16(W2t, act, w, quad, nl, acc);
    __syncthreads();   // all reads of h done before overwrite with agg
    {
        float bb0 = b2[w * 32 + nl], bb1 = b2[w * 32 + 16 + nl];
        #pragma unroll
        for (int mt = 0; mt < 4; mt++)
            #pragma unroll
            for (int r = 0; r < 4; r++) {
                int m  = mt * 16 + quad * 4 + r;
                float cn  = cnLds[m];
                float has = (cn > 0.f) ? 1.f : 0.f;
                unsigned pk = meanb[m * 64 + w * 16 + nl];
                float a0 = bf2f((unsigned short)(pk & 0xffff))
                         - (acc[mt][0][r] + bb0) * has;
                float a1 = bf2f((unsigned short)(pk >> 16))
                         - (acc[mt][1][r] + bb1) * has;
                act[m * PAD_K + w * 32 + nl]      = f2bf(a0);
                act[m * PAD_K + w * 32 + 16 + nl] = f2bf(a1);
            }
    }
    __syncthreads();

    // ---- GEMM3: u = agg @ Wu; y = x + u + bu; LayerNorm ----
    gemm16(Wut, act, w, quad, nl, acc);
    float y[4][2][4];
    {
        float bb0 = bu[w * 32 + nl], bb1 = bu[w * 32 + 16 + nl];
        #pragma unroll
        for (int mt = 0; mt < 4; mt++)
            #pragma unroll
            for (int r = 0; r < 4; r++) {
                int m = mt * 16 + quad * 4 + r;
                float x0 = bf2f(xbuf[m * PAD_K + w * 32 + nl]);
                float x1 = bf2f(xbuf[m * PAD_K + w * 32 + 16 + nl]);
                float y0 = x0 + acc[mt][0][r] + bb0;
                float y1 = x1 + acc[mt][1][r] + bb1;
                y[mt][0][r] = y0;
                y[mt][1][r] = y1;
                float s1 = y0 + y1;
                float s2 = y0 * y0 + y1 * y1;
                #pragma unroll
                for (int o = 1; o < 16; o <<= 1) {
                    s1 += __shfl_xor(s1, o, 64);
                    s2 += __shfl_xor(s2, o, 64);
                }
                if (nl == 0) { lnS[m][w] = s1; lnQ[m][w] = s2; }
            }
    }
    __syncthreads();
    if (t < 64) {
        float s = lnS[t][0] + lnS[t][1] + lnS[t][2] + lnS[t][3];
        float q = lnQ[t][0] + lnQ[t][1] + lnQ[t][2] + lnQ[t][3];
        float mu  = s * (1.0f / HIDDEN);
        float var = q * (1.0f / HIDDEN) - mu * mu;
        lnMu[t] = mu;
        lnRs[t] = rsqrtf(var + LN_EPS);
    }
    __syncthreads();
    {
        float g0 = gamma[w * 32 + nl], g1 = gamma[w * 32 + 16 + nl];
        float e0 = beta[w * 32 + nl],  e1 = beta[w * 32 + 16 + nl];
        #pragma unroll
        for (int mt = 0; mt < 4; mt++)
            #pragma unroll
            for (int r = 0; r < 4; r++) {
                int m  = mt * 16 + quad * 4 + r;
                int gr = row0 + m;
                if (gr < Np) {
                    float mu = lnMu[m], rs = lnRs[m];
                    out[(size_t)gr * HIDDEN + w * 32 + nl] =
                        (y[mt][0][r] - mu) * rs * g0 + e0;
                    out[(size_t)gr * HIDDEN + w * 32 + 16 + nl] =
                        (y[mt][1][r] - mu) * rs * g1 + e1;
                }
            }
    }
}

extern "C" void kernel_launch(void* const* d_in, const int* in_sizes, int n_in,
                              void* d_out, int out_size, void* d_ws, size_t ws_size,
                              hipStream_t stream) {
    const float* xp    = (const float*)d_in[0];
    const float* xc    = (const float*)d_in[1];
    const int*   src   = (const int*)d_in[2];
    const int*   dst   = (const int*)d_in[3];
    const float* W1    = (const float*)d_in[4];
    const float* b1    = (const float*)d_in[5];
    const float* W2    = (const float*)d_in[6];
    const float* b2    = (const float*)d_in[7];
    const float* Wu    = (const float*)d_in[8];
    const float* bu    = (const float*)d_in[9];
    const float* gamma = (const float*)d_in[10];
    const float* beta  = (const float*)d_in[11];

    const int Np = in_sizes[0] / HIDDEN;
    const int Nc = in_sizes[1] / HIDDEN;
    const int E  = in_sizes[2];

    char* ws = (char*)d_ws;
    size_t off = 0;
    auto alloc = [&](size_t bytes) {
        char* p = ws + off;
        off += (bytes + 15) & ~size_t(15);
        return p;
    };
    int*            slots = (int*)           alloc((size_t)Np * SLOT * sizeof(int));
    int*            cnt_i = (int*)           alloc((size_t)Np * sizeof(int));
    unsigned short* W1t   = (unsigned short*)alloc(HIDDEN * HIDDEN * sizeof(unsigned short));
    unsigned short* W2t   = (unsigned short*)alloc(HIDDEN * HIDDEN * sizeof(unsigned short));
    unsigned short* Wut   = (unsigned short*)alloc(HIDDEN * HIDDEN * sizeof(unsigned short));
    size_t offBeforeXcp = off;
    unsigned*       xcp   = (unsigned*)      alloc((size_t)Nc * 64 * sizeof(unsigned));
    int usePacked = (off <= ws_size) ? 1 : 0;   // fall back if ws too small
    if (!usePacked) off = offBeforeXcp;

    hipMemsetAsync(cnt_i, 0, (size_t)Np * sizeof(int), stream);

    int wb = (HIDDEN * HIDDEN + 255) / 256;
    prep_weights<<<wb, 256, 0, stream>>>(W1, W2, Wu, W1t, W2t, Wut);

    int eb = (E + 255) / 256;
    edge_scatter_pad<<<eb, 256, 0, stream>>>(src, dst, cnt_i, slots, E);

    if (usePacked) {
        int pb = (Nc + 3) / 4;
        pack_xc<<<pb, 256, 0, stream>>>(xc, xcp, Nc);
    }

    int pblocks = (Np + 63) / 64;
    parent_fused<<<pblocks, 256, 0, stream>>>(xp, W1t, b1, W2t, b2, Wut, bu,
                                              gamma, beta, slots, cnt_i,
                                              xcp, xc, usePacked,
                                              (float*)d_out, Np);
}